// Round 16
// baseline (1210.249 us; speedup 1.0000x reference)
//
#include <hip/hip_runtime.h>
#include <math.h>

typedef __attribute__((ext_vector_type(8))) short short8;
typedef __attribute__((ext_vector_type(4))) float f32x4;

#define TSTEPS 1024
#define BATCH  64
#define CDIM   512
#define CAP    256   // segments per group-chunk (ring-row capacity)
#define NPH    4     // ring phases

// ---- workspace layout ----
// HEXW: tagged u32 [16 groups][NPH][CAP rows][512 cols] = 32 MiB
#define HEXW_OFF   0
#define HEXW_BYTES ((size_t)16 * NPH * CAP * 512 * 4)
#define GSEG_OFF   (HEXW_OFF + HEXW_BYTES)
#define GSEG_BYTES ((size_t)65536 * 4)
#define GCNT_OFF   (GSEG_OFF + GSEG_BYTES)
#define GCNT_BYTES (1024 * 4)
#define FLG_OFF    (GCNT_OFF + GCNT_BYTES)
#define FLG_BYTES  (256 * 16 * 4)
#define SEGT_OFF   (FLG_OFF + FLG_BYTES)
#define SEGT_BYTES ((size_t)64 * 1024 * 4)
#define WS_NEED    (SEGT_OFF + SEGT_BYTES)

// ---- main kernel LDS map (dynamic, bytes) ----
// HA dbuf 2x16K @0 ; XA dbuf 2x16K @32768 ; CSEG f32[256][32] @65536 ;
// GC u32[1024] @98304 ; SEGL u32[256] @102400
#define SMEM_BYTES 103424   // > 81920 -> 1 block/CU

__device__ __forceinline__ unsigned short f2bf(float x) {
  unsigned u = __builtin_bit_cast(unsigned, x);
  unsigned r = (u + 0x7FFFu + ((u >> 16) & 1u)) >> 16;
  return (unsigned short)r;
}
__device__ __forceinline__ short8 pack8(float4 lo, float4 hi) {
  short8 r;
  r[0] = (short)f2bf(lo.x); r[1] = (short)f2bf(lo.y);
  r[2] = (short)f2bf(lo.z); r[3] = (short)f2bf(lo.w);
  r[4] = (short)f2bf(hi.x); r[5] = (short)f2bf(hi.y);
  r[6] = (short)f2bf(hi.z); r[7] = (short)f2bf(hi.w);
  return r;
}
__device__ __forceinline__ float sigm(float z) { return 1.0f / (1.0f + __expf(-z)); }
__device__ __forceinline__ float tanh_f(float x) {
  return 2.0f / (1.0f + __expf(-2.0f * x)) - 1.0f;
}
__device__ __forceinline__ void backoff(int rnd) {
  if (rnd == 1) __builtin_amdgcn_s_sleep(1);
  else if (rnd >= 2) __builtin_amdgcn_s_sleep(2);
}
// fire-and-forget atomic swap: executes at the MALL atomic unit -> immediately
// globally visible (no lazy write-drain). No-return form, no waitcnt.
__device__ __forceinline__ void st_swap_u32(unsigned* p, unsigned v) {
  asm volatile("global_atomic_swap %0, %1, off" ::"v"(p), "v"(v) : "memory");
}
// LDS-only barrier: no vmcnt(0) drain (y/flush stores stay in flight;
// cross-block visibility is tag-certified). Rule-18 fences included.
__device__ __forceinline__ void soft_barrier() {
  __builtin_amdgcn_sched_barrier(0);
  asm volatile("s_waitcnt lgkmcnt(0)" ::: "memory");
  __builtin_amdgcn_s_barrier();
  __builtin_amdgcn_sched_barrier(0);
}

// chunk-boundary only: poll 15 peer flags
__device__ __forceinline__ void pollg(const unsigned* flg, int g, int cg,
                                      unsigned tgt, int lane) {
  const int idx = lane & 15;
  int rnd = 0;
  while (true) {
    unsigned v = (idx == cg)
                     ? 0xffffffffu
                     : __hip_atomic_load(&flg[(g * 16 + idx) * 16],
                                         __ATOMIC_RELAXED, __HIP_MEMORY_SCOPE_AGENT);
    if (__all((int)(v >= tgt))) break;
    backoff(++rnd > 2 ? 2 : rnd);
  }
  asm volatile("" ::: "memory");
}

// ============ kernel 0: segment extraction + counting sort by length desc ====
// GSEG[rank] packed: len(11)<<17 | start(10)<<7 | b(6)<<1 | seed(1).
// Rank p sorted by len desc; group g owns ranks p%16==g. GCNT[r] = #len>r.
__global__ __launch_bounds__(512) void seg_setup(const void* __restrict__ rst,
    unsigned* __restrict__ GSEG, unsigned* __restrict__ GCNT,
    unsigned* __restrict__ SEGT) {
  __shared__ unsigned long long RM[1024];     // per-t batch mask
  __shared__ unsigned long long BM[64][17];   // per-b time mask (16 u64 + pad)
  __shared__ unsigned hist[1025], GCl[1025], cur[1025];
  __shared__ unsigned nsegb[64];
  __shared__ int s_oki, s_okf, s_oddnz;
  const int tid = threadIdx.x, lane = tid & 63, wv = tid >> 6;
  if (tid == 0) { s_oki = 1; s_okf = 1; s_oddnz = 0; }
  __syncthreads();
  {
    int oki = 1, okf = 1, oddnz = 0;
    for (int i = tid; i < 1024; i += 512) {
      unsigned v = ((const unsigned*)rst)[i];
      oki &= (v <= 1u);
      okf &= (v == 0u || v == 0x3F800000u);
      if ((i & 1) && v != 0u) oddnz = 1;
    }
    if (!oki) atomicAnd(&s_oki, 0);
    if (!okf) atomicAnd(&s_okf, 0);
    if (oddnz) atomicOr(&s_oddnz, 1);
  }
  __syncthreads();
  const int mode = s_oki ? (s_oddnz ? 0 : 3) : (s_okf ? 2 : 1);
  for (int tt = wv; tt < 1024; tt += 8) {
    int idx = tt * BATCH + lane;
    bool r;
    if (mode == 0)      r = ((const int*)rst)[idx] != 0;
    else if (mode == 1) r = ((const unsigned char*)rst)[idx] != 0;
    else if (mode == 2) r = ((const float*)rst)[idx] != 0.0f;
    else                r = ((const int*)rst)[2 * idx] != 0;
    unsigned long long bm = __ballot((int)r);
    if (lane == 0) RM[tt] = bm;
  }
  for (int i = tid; i < 1025; i += 512) { hist[i] = 0; cur[i] = 0; }
  __syncthreads();
  // ballot transpose: BM[b][w] bit t' = reset[w*64+t'][b]
  for (int idx = wv; idx < 1024; idx += 8) {
    int b = idx >> 4, w = idx & 15;
    unsigned long long bit = (RM[w * 64 + lane] >> b) & 1ull;
    unsigned long long m = __ballot((int)(bit != 0ull));
    if (lane == 0) BM[b][w] = m;
  }
  __syncthreads();
  if (tid < 64) {
    int b = tid; unsigned cnt = 0; int s = 0;
    unsigned seed0 = (BM[b][0] & 1ull) ? 0u : 1u;
    for (int w = 0; w < 16; ++w) {
      unsigned long long m = BM[b][w];
      if (w == 0) m &= ~1ull;
      while (m) {
        int t = w * 64 + __builtin_ctzll(m);
        m &= m - 1;
        unsigned len = (unsigned)(t - s);
        unsigned sd = (s == 0) ? seed0 : 0u;
        SEGT[b * 1024 + cnt++] =
            (len << 17) | ((unsigned)s << 7) | ((unsigned)b << 1) | sd;
        atomicAdd(&hist[len], 1u);
        s = t;
      }
    }
    { unsigned len = (unsigned)(1024 - s);
      unsigned sd = (s == 0) ? seed0 : 0u;
      SEGT[b * 1024 + cnt++] =
          (len << 17) | ((unsigned)s << 7) | ((unsigned)b << 1) | sd;
      atomicAdd(&hist[len], 1u); }
    nsegb[b] = cnt;
  }
  __syncthreads();
  if (tid == 0) {
    unsigned acc = 0;
    for (int r = 1023; r >= 0; --r) { acc += hist[r + 1]; GCl[r] = acc; }
    GCl[1024] = 0;
  }
  __syncthreads();
  if (tid < 64) {
    int b = tid;
    for (unsigned k = 0; k < nsegb[b]; ++k) {
      unsigned v = SEGT[b * 1024 + k];
      unsigned len = v >> 17;
      unsigned p = GCl[len] + atomicAdd(&cur[len], 1u);
      GSEG[p] = v;
    }
  }
  __syncthreads();
  for (int i = tid; i < 1024; i += 512) GCNT[i] = GCl[i];
}

// ============ kernel 1: depth-parallel LSTM, tagged 4-phase ring exchange ====
// Per tile: write prefetched x -> poll/stage h -> soft barrier (lgkm only) ->
// issue next tile's x loads -> 32 MFMA -> 4-shfl gate transpose -> cell ->
// per-lane tagged flush (atomic-swap in tail rounds for prompt visibility).
__global__ __launch_bounds__(512, 1) void rlstm_seq(
    const float* __restrict__ x, const float* __restrict__ h0,
    const float* __restrict__ c0, const float* __restrict__ whh,
    const float* __restrict__ wih, const float* __restrict__ bih,
    const float* __restrict__ bhh, float* __restrict__ y,
    unsigned* __restrict__ hexw, unsigned* __restrict__ flg,
    const unsigned* __restrict__ GSEG, const unsigned* __restrict__ GCNT) {
  extern __shared__ __align__(16) char smem[];
  float* CSEG = (float*)(smem + 65536);
  unsigned* GC = (unsigned*)(smem + 98304);
  unsigned* SEGL = (unsigned*)(smem + 102400);

  const int tid = threadIdx.x, bid = blockIdx.x;
  const int g = bid >> 4, cg = bid & 15;
  const int lane = tid & 63, wv = tid >> 6;
  const int grp = lane >> 4, lr = lane & 15;
  const int gt = lr >> 2, j = lr & 3;
  const int lcol = wv * 4 + j;
  const int cglob = cg * 32 + lcol;
  const int nglob = gt * CDIM + cglob;
  const int srow = 2 * wv + (lane >> 5);
  const int wcol = lane & 31;
  const int swz = (srow & 7) << 4;

  // both weight slices register-resident: 128 VGPR/wave
  short8 wfrag[16], wfrag2[16];
#pragma unroll
  for (int kk = 0; kk < 16; ++kk) {
    const float* s = whh + (size_t)nglob * CDIM + kk * 32 + grp * 8;
    float4 lo = *(const float4*)s, hi = *(const float4*)(s + 4);
    wfrag[kk] = pack8(lo, hi);
    const float* s2 = wih + (size_t)nglob * CDIM + kk * 32 + grp * 8;
    float4 lo2 = *(const float4*)s2, hi2 = *(const float4*)(s2 + 4);
    wfrag2[kk] = pack8(lo2, hi2);
  }
  const float bsum = bih[nglob] + bhh[nglob];

  for (int i = tid; i < 1024; i += 512) GC[i] = GCNT[i];
  __syncthreads();

  const unsigned G0 = GC[0];
  const unsigned totg = (G0 > (unsigned)g) ? ((G0 - g + 15u) >> 4) : 0u;
  const int nchunks = (int)((totg + CAP - 1) / CAP);
  unsigned tg = 0, fv = 0;
  float4 xv[4] = {{0,0,0,0},{0,0,0,0},{0,0,0,0},{0,0,0,0}};  // x prefetch regs

  for (int chunk = 0; chunk < nchunks; ++chunk) {
    const unsigned cb = (unsigned)chunk * CAP;
    int M0;
    { unsigned t2 = totg;
      M0 = (t2 > cb) ? (int)((t2 - cb > CAP) ? CAP : (t2 - cb)) : 0; }
    if (M0 == 0) break;
    if (chunk > 0) pollg(flg, g, cg, fv, lane);  // peers exited prior chunk

    ++tg;  // seed tag (consumed by round 0)
    // ---- seed phase 0 + CSEG + SEGL ----
    for (int i = tid >> 4; i < M0; i += 32) {
      int c2 = (tid & 15) * 2;
      unsigned sv = GSEG[(size_t)(cb + i) * 16 + g];
      if ((tid & 15) == 0) SEGL[i] = sv;
      int b = (sv >> 1) & 63;
      float ha = 0.f, hb = 0.f, ca = 0.f, cbv = 0.f;
      if (sv & 1u) {
        const float* hp = h0 + (size_t)b * CDIM + cg * 32 + c2;
        ha = hp[0]; hb = hp[1];
        const float* cp = c0 + (size_t)b * CDIM + cg * 32 + c2;
        ca = cp[0]; cbv = cp[1];
      }
      CSEG[i * 32 + c2] = ca; CSEG[i * 32 + c2 + 1] = cbv;
      unsigned lo = ((unsigned)f2bf(ha) << 16) | tg;
      unsigned hi2 = ((unsigned)f2bf(hb) << 16) | tg;
      unsigned long long w = ((unsigned long long)hi2 << 32) | lo;
      __hip_atomic_store((unsigned long long*)hexw +
                             ((size_t)(g * NPH + 0) * CAP + i) * 256 + cg * 16 +
                             (tid & 15),
                         w, __ATOMIC_RELAXED, __HIP_MEMORY_SCOPE_AGENT);
    }
    __syncthreads();  // SEGL/CSEG ready

    // prologue: issue x loads for (round 0, tile 0)
    { int i = srow;
      if (i < M0) {
        unsigned sv = SEGL[i];
        int b = (sv >> 1) & 63, s0 = (sv >> 7) & 1023;
        const float* xr = x + ((size_t)s0 * BATCH + b) * CDIM;
        xv[0] = *(const float4*)(xr + wcol * 8);
        xv[1] = *(const float4*)(xr + wcol * 8 + 4);
        xv[2] = *(const float4*)(xr + (wcol + 32) * 8);
        xv[3] = *(const float4*)(xr + (wcol + 32) * 8 + 4);
      }
    }

    // ---- depth rounds ----
    for (int r = 0;; ++r) {
      if (r >= 1024) break;
      int M;
      { unsigned Gr = GC[r];
        unsigned t2 = (Gr > (unsigned)g) ? ((Gr - g + 15u) >> 4) : 0u;
        M = (t2 > cb) ? (int)((t2 - cb > CAP) ? CAP : (t2 - cb)) : 0; }
      if (M == 0) break;
      int Mn = 0;
      if (r + 1 < 1024) {
        unsigned Gn = GC[r + 1];
        unsigned t2 = (Gn > (unsigned)g) ? ((Gn - g + 15u) >> 4) : 0u;
        Mn = (t2 > cb) ? (int)((t2 - cb > CAP) ? CAP : (t2 - cb)) : 0;
      }
      const int ph = r & (NPH - 1), phw = (r + 1) & (NPH - 1);
      const unsigned wtg = tg + 1;
      unsigned* const wbase = hexw + (size_t)(g * NPH + phw) * CAP * 512;
      const bool uswap = (Mn <= 64);  // tail: prompt-visibility atomic flush

      for (int i0 = 0; i0 < M; i0 += 16) {
        const int p = ((i0 >> 4) + r) & 1;
        char* habuf = smem + p * 16384;
        char* xabuf = smem + 32768 + p * 16384;

        // write prefetched x regs to LDS (loads issued ~1 tile ago)
        { int i = i0 + srow;
          if (i < M) {
            *(short8*)(xabuf + srow * 1024 + ((wcol * 16) ^ swz)) =
                pack8(xv[0], xv[1]);
            *(short8*)(xabuf + srow * 1024 + (((wcol + 32) * 16) ^ swz)) =
                pack8(xv[2], xv[3]);
          }
        }
        // poll + stage h_prev tile (tagged words ARE the handshake)
        { int i = i0 + srow;
          if (i < M) {
            const unsigned long long* hq = (const unsigned long long*)hexw +
                ((size_t)(g * NPH + ph) * CAP + i) * 256;
            unsigned long long v8[8];
            unsigned pn = 0xffu;
            int rnd = 0;
            do {
              backoff(rnd > 2 ? 2 : rnd);
              ++rnd;
#pragma unroll
              for (int k = 0; k < 8; ++k)
                if (pn & (1u << k))
                  v8[k] = __hip_atomic_load(hq + wcol + 32 * k, __ATOMIC_RELAXED,
                                            __HIP_MEMORY_SCOPE_AGENT);
              unsigned np = 0;
#pragma unroll
              for (int k = 0; k < 8; ++k) {
                unsigned lo = (unsigned)v8[k];
                unsigned hi = (unsigned)(v8[k] >> 32);
                if (((lo ^ tg) | (hi ^ tg)) & 0xffffu) np |= 1u << k;
              }
              pn = np;
            } while (__any((int)pn));
#pragma unroll
            for (int k = 0; k < 8; ++k) {
              unsigned lo = (unsigned)v8[k];
              unsigned hi = (unsigned)(v8[k] >> 32);
              unsigned pk = (lo >> 16) | (hi & 0xffff0000u);
              int m = wcol + 32 * k;
              *(unsigned*)(habuf + srow * 1024 + ((m * 4) ^ swz)) = pk;
            }
          }
        }
        soft_barrier();  // LDS-only: y/flush stores stay in flight

        // issue x loads for NEXT tile (hidden under MFMA + next poll)
        { int nii = i0 + 16, nbound = M, nr = r;
          if (nii >= M) { nii = 0; nbound = Mn; nr = r + 1; }
          int i = nii + srow;
          if (i < nbound) {
            unsigned sv = SEGL[i];
            int b = (sv >> 1) & 63, s0 = (sv >> 7) & 1023;
            const float* xr = x + ((size_t)(s0 + nr) * BATCH + b) * CDIM;
            xv[0] = *(const float4*)(xr + wcol * 8);
            xv[1] = *(const float4*)(xr + wcol * 8 + 4);
            xv[2] = *(const float4*)(xr + (wcol + 32) * 8);
            xv[3] = *(const float4*)(xr + (wcol + 32) * 8 + 4);
          }
        }

        // recurrent + input GEMMs: dual chains each
        f32x4 h0a = {0.f,0.f,0.f,0.f}, h1a = {0.f,0.f,0.f,0.f};
        f32x4 x0a = {0.f,0.f,0.f,0.f}, x1a = {0.f,0.f,0.f,0.f};
#pragma unroll
        for (int kk = 0; kk < 16; ++kk) {
          const int aoff = ((kk * 64 + grp * 16) ^ ((lr & 7) << 4));
          short8 a = *(const short8*)(habuf + lr * 1024 + aoff);
          short8 ax = *(const short8*)(xabuf + lr * 1024 + aoff);
          if (kk & 1) {
            h1a = __builtin_amdgcn_mfma_f32_16x16x32_bf16(a, wfrag[kk], h1a, 0, 0, 0);
            x1a = __builtin_amdgcn_mfma_f32_16x16x32_bf16(ax, wfrag2[kk], x1a, 0, 0, 0);
          } else {
            h0a = __builtin_amdgcn_mfma_f32_16x16x32_bf16(a, wfrag[kk], h0a, 0, 0, 0);
            x0a = __builtin_amdgcn_mfma_f32_16x16x32_bf16(ax, wfrag2[kk], x0a, 0, 0, 0);
          }
        }
        f32x4 acc = (h0a + h1a) + (x0a + x1a);

        // ---- 4x4 gate transpose across gt-lanes (4 shfl), then one cell ----
        float a0 = acc[0] + bsum, a1 = acc[1] + bsum;
        float a2 = acc[2] + bsum, a3 = acc[3] + bsum;
        const int b0 = gt & 1, b1 = (gt >> 1) & 1;
        float sA0 = b0 ? a0 : a1;
        float sA1 = b0 ? a2 : a3;
        float rA0 = __shfl_xor(sA0, 4);
        float rA1 = __shfl_xor(sA1, 4);
        float k0 = b0 ? a1 : a0;
        float k1 = b0 ? a3 : a2;
        float sB0 = b1 ? k0 : k1;
        float sB1 = b1 ? rA0 : rA1;
        float rB0 = __shfl_xor(sB0, 8);
        float rB1 = __shfl_xor(sB1, 8);
        float m0 = b1 ? k1 : k0;
        float m1 = b1 ? rA1 : rA0;
        float gi = (gt == 0) ? m0 : (gt == 1) ? m1 : (gt == 2) ? rB0 : rB1;
        float gf = (gt == 1) ? m0 : (gt == 0) ? m1 : (gt == 3) ? rB0 : rB1;
        float gg = (gt == 2) ? m0 : (gt == 3) ? m1 : (gt == 0) ? rB0 : rB1;
        float go = (gt == 3) ? m0 : (gt == 2) ? m1 : (gt == 1) ? rB0 : rB1;

        const int i = i0 + grp * 4 + gt;    // this lane's row
        if (i < M) {
          float cprev = CSEG[i * 32 + lcol];
          float cn = sigm(gf) * cprev + sigm(gi) * tanh_f(gg);
          CSEG[i * 32 + lcol] = cn;
          float hsel = sigm(go) * tanh_f(cn);
          if (i < Mn) {
            unsigned w = ((unsigned)f2bf(hsel) << 16) | wtg;
            unsigned* hp = wbase + (size_t)i * 512 + cglob;
            if (uswap) st_swap_u32(hp, w);
            else __hip_atomic_store(hp, w, __ATOMIC_RELAXED,
                                    __HIP_MEMORY_SCOPE_AGENT);
          }
          unsigned sv = SEGL[i];
          int rowm = (int)((((sv >> 7) & 1023) + r) * BATCH + ((sv >> 1) & 63));
          y[(size_t)rowm * CDIM + cglob] = hsel;
        }
      }
      ++tg;  // next round's input tag
    }

    // chunk done: post flag so peers may reuse phase 0 for next chunk's seed
    ++fv;
    asm volatile("s_waitcnt vmcnt(0)" ::: "memory");
    __syncthreads();
    if (tid == 0)
      __hip_atomic_store(&flg[(g * 16 + cg) * 16], fv, __ATOMIC_RELAXED,
                         __HIP_MEMORY_SCOPE_AGENT);
  }
}

extern "C" void kernel_launch(void* const* d_in, const int* in_sizes, int n_in,
                              void* d_out, int out_size, void* d_ws, size_t ws_size,
                              hipStream_t stream) {
  (void)in_sizes; (void)n_in; (void)out_size;
  const float* x = (const float*)d_in[0];
  const void* rstp = (const void*)d_in[1];
  const float* h0 = (const float*)d_in[2];
  const float* c0 = (const float*)d_in[3];
  const float* wih = (const float*)d_in[4];
  const float* whh = (const float*)d_in[5];
  const float* bih = (const float*)d_in[6];
  const float* bhh = (const float*)d_in[7];
  float* y = (float*)d_out;

  if (ws_size < WS_NEED) return;  // diagnosable clean failure

  unsigned* hexw = (unsigned*)((char*)d_ws + HEXW_OFF);
  unsigned* GSEG = (unsigned*)((char*)d_ws + GSEG_OFF);
  unsigned* GCNT = (unsigned*)((char*)d_ws + GCNT_OFF);
  unsigned* flg = (unsigned*)((char*)d_ws + FLG_OFF);
  unsigned* SEGT = (unsigned*)((char*)d_ws + SEGT_OFF);

  // zero tags (tag 0 never used) + flags; ~32 MB, L3-speed
  (void)hipMemsetAsync(d_ws, 0, FLG_OFF + FLG_BYTES, stream);

  seg_setup<<<dim3(1), dim3(512), 0, stream>>>(rstp, GSEG, GCNT, SEGT);

  (void)hipFuncSetAttribute(reinterpret_cast<const void*>(rlstm_seq),
                            hipFuncAttributeMaxDynamicSharedMemorySize, SMEM_BYTES);
  void* args[] = {(void*)&x,    (void*)&h0,  (void*)&c0,   (void*)&whh,
                  (void*)&wih,  (void*)&bih, (void*)&bhh,  (void*)&y,
                  (void*)&hexw, (void*)&flg, (void*)&GSEG, (void*)&GCNT};
  (void)hipLaunchCooperativeKernel((void*)rlstm_seq, dim3(256), dim3(512), args,
                                   SMEM_BYTES, stream);
}